// Round 2
// baseline (3374.845 us; speedup 1.0000x reference)
//
#include <hip/hip_runtime.h>

// ---------------------------------------------------------------------------
// GaussianGradientLSTMPolicy on MI355X
//   A0: fp32 -> bf16 converts (x, weights), bias fusions, flag init
//   A2: shared = leaky_relu(x @ W1^T + b1)                  [131072 x 256]
//   A3: ig     = shared @ W_ih^T + (b_ih + b_hh)  (permuted)[131072 x 1024]
//   B : persistent-register LSTM scan, block pairs exchange h halves via LLC
//   C : means = tanh(pre@Wm^T+bm), stds = softplus(pre@Ws^T+bs)+eps
// Aliasing (fixed in R2):
//   - x_bf16 lives in d_out[0 .. 32MiB) (means+stds region), consumed by A2
//   - ig (bf16) lives in the d_out hidden_outputs region with a PERMUTED
//     layout such that the bytes block (g,ph) reads as ig[t] are exactly the
//     bytes it writes as hid[t]:
//       idx_u16(t,b,q,ph,jl) = t*262144 + (q>>1)*131072 + b*512
//                              + ph*256 + (q&1)*128 + jl
//     -> byte set {s*262144 + b*1024 + ph*512 + [0,512)} == hid[t] writes of
//     (s, b in [b0,b0+16), jcol in ph*128+[0,128)). Per-block aliasing only;
//     within a block the vmcnt(0)-before-s_barrier drain orders all ig[t]
//     loads (prefetched in step t-1) before any hid[t] store (step t).
// ---------------------------------------------------------------------------

typedef __attribute__((ext_vector_type(8))) short short8;
typedef __attribute__((ext_vector_type(4))) float f32x4;
typedef __attribute__((ext_vector_type(4))) unsigned short u16x4;
typedef unsigned short u16;
typedef unsigned int   u32;

// ws layout (bytes)
constexpr size_t OFF_SH   = 0;                      // shared bf16   67108864
constexpr size_t OFF_PRE  = 67108864;               // pre bf16      67108864
constexpr size_t OFF_W1   = 134217728;              // W1 bf16          65536
constexpr size_t OFF_WIH  = OFF_W1   + 65536;       // W_ih bf16       524288
constexpr size_t OFF_WHH  = OFF_WIH  + 524288;      // W_hh bf16       524288
constexpr size_t OFF_WCAT = OFF_WHH  + 524288;      // [Wm;Ws] bf16     32768
constexpr size_t OFF_BIG  = OFF_WCAT + 32768;       // b_ih+b_hh f32     4096
constexpr size_t OFF_BCAT = OFF_BIG  + 4096;        // [bm;bs] f32        256
constexpr size_t OFF_X    = OFF_BCAT + 256;         // h2 exchange     524288
constexpr size_t OFF_FLAG = OFF_X    + 524288;      // flags             2048
// total ~136 MB

__device__ __forceinline__ u16 f2bf(float f) {
  union { float f; u32 u; } v; v.f = f;
  u32 u = v.u;
  return (u16)((u + 0x7fffu + ((u >> 16) & 1u)) >> 16);   // RNE
}
__device__ __forceinline__ float bf2f(u16 h) {
  union { u32 u; float f; } v; v.u = ((u32)h) << 16; return v.f;
}
__device__ __forceinline__ float fsigmoid(float x) {
  return 1.0f / (1.0f + __expf(-x));
}
__device__ __forceinline__ float ftanh(float x) {
  return 1.0f - 2.0f / (__expf(2.0f * x) + 1.0f);
}

// ---------------------------------------------------------------- converts
__global__ void k_conv_x(const float* __restrict__ x, u16* __restrict__ o) {
  const size_t stride = (size_t)gridDim.x * blockDim.x;
  for (size_t i = (size_t)blockIdx.x * blockDim.x + threadIdx.x;
       i < 16777216 / 4; i += stride) {
    f32x4 v = ((const f32x4*)x)[i];
    u16x4 r;
    r[0] = f2bf(v[0]); r[1] = f2bf(v[1]); r[2] = f2bf(v[2]); r[3] = f2bf(v[3]);
    ((u16x4*)o)[i] = r;
  }
}

__global__ void k_small(const float* __restrict__ W1, const float* __restrict__ Wih,
                        const float* __restrict__ Whh, const float* __restrict__ Wm,
                        const float* __restrict__ Ws,  const float* __restrict__ bih,
                        const float* __restrict__ bhh, const float* __restrict__ bm,
                        const float* __restrict__ bs,
                        u16* __restrict__ W1b, u16* __restrict__ Wihb,
                        u16* __restrict__ Whhb, u16* __restrict__ Wcatb,
                        float* __restrict__ bigv, float* __restrict__ bcatv,
                        u32* __restrict__ flags) {
  const int stride = gridDim.x * blockDim.x;
  const int i0 = blockIdx.x * blockDim.x + threadIdx.x;
  for (int i = i0; i < 32768;  i += stride) W1b[i]  = f2bf(W1[i]);
  for (int i = i0; i < 262144; i += stride) Wihb[i] = f2bf(Wih[i]);
  for (int i = i0; i < 262144; i += stride) Whhb[i] = f2bf(Whh[i]);
  for (int i = i0; i < 8192;   i += stride) Wcatb[i]        = f2bf(Wm[i]);
  for (int i = i0; i < 8192;   i += stride) Wcatb[8192 + i] = f2bf(Ws[i]);
  for (int i = i0; i < 1024;   i += stride) bigv[i] = bih[i] + bhh[i];
  for (int i = i0; i < 32;     i += stride) bcatv[i]      = bm[i];
  for (int i = i0; i < 32;     i += stride) bcatv[32 + i] = bs[i];
  for (int i = i0; i < 512;    i += stride) flags[i] = 0;
}

// ------------------------------------------------------------ generic GEMM
// C[M,N] = epi(A[M,K] @ W[N,K]^T + bias), bf16 in, fp32 acc.
// EPI 0: leaky_relu -> bf16 out (ld = N)
// EPI 1: bf16 out, permuted so scan-block (g,ph)'s ig[t] bytes == its hid[t]
// EPI 2: heads: n<32 -> tanh -> means(f32); n>=32 -> softplus+eps -> stds
template <int K, int EPI>
__global__ __launch_bounds__(256) void gemm_bt(const u16* __restrict__ A,
                                               const u16* __restrict__ W,
                                               const float* __restrict__ bias,
                                               void* __restrict__ outp, int N) {
  __shared__ __align__(16) u16 As[64 * 40];   // +8 pad: 2-way banks only
  __shared__ __align__(16) u16 Wt[64 * 40];
  const int tid  = threadIdx.x;
  const int lane = tid & 63;
  const int wv   = tid >> 6;
  const int quad = lane >> 4, l15 = lane & 15;
  const int wm = wv & 1, wn = wv >> 1;
  const size_t m0 = (size_t)blockIdx.x * 64;
  const int    n0 = blockIdx.y * 64;
  const int ldr  = tid >> 2;
  const int lseg = (tid & 3) * 8;

  const u16* Ag = A + (m0 + ldr) * K + lseg;
  const u16* Wg = W + (size_t)(n0 + ldr) * K + lseg;

  f32x4 acc[2][2] = {};

#pragma unroll 1
  for (int kc = 0; kc < K; kc += 32) {
    *(short8*)&As[ldr * 40 + lseg] = *(const short8*)(Ag + kc);
    *(short8*)&Wt[ldr * 40 + lseg] = *(const short8*)(Wg + kc);
    __syncthreads();
    short8 a0 = *(const short8*)&As[(wm * 32 + l15) * 40 + quad * 8];
    short8 a1 = *(const short8*)&As[(wm * 32 + 16 + l15) * 40 + quad * 8];
    short8 b0 = *(const short8*)&Wt[(wn * 32 + l15) * 40 + quad * 8];
    short8 b1 = *(const short8*)&Wt[(wn * 32 + 16 + l15) * 40 + quad * 8];
    acc[0][0] = __builtin_amdgcn_mfma_f32_16x16x32_bf16(a0, b0, acc[0][0], 0, 0, 0);
    acc[1][0] = __builtin_amdgcn_mfma_f32_16x16x32_bf16(a1, b0, acc[1][0], 0, 0, 0);
    acc[0][1] = __builtin_amdgcn_mfma_f32_16x16x32_bf16(a0, b1, acc[0][1], 0, 0, 0);
    acc[1][1] = __builtin_amdgcn_mfma_f32_16x16x32_bf16(a1, b1, acc[1][1], 0, 0, 0);
    __syncthreads();
  }

#pragma unroll
  for (int mi = 0; mi < 2; mi++)
#pragma unroll
    for (int ni = 0; ni < 2; ni++) {
      const int nl   = wn * 32 + ni * 16 + l15;   // 0..63 within tile
      const int ncol = n0 + nl;                   // global col
      const float bv = bias[ncol];
#pragma unroll
      for (int r = 0; r < 4; r++) {
        const size_t m = m0 + wm * 32 + mi * 16 + quad * 4 + r;
        float v = acc[mi][ni][r] + bv;
        if (EPI == 0) {
          v = v > 0.0f ? v : 0.01f * v;
          ((u16*)outp)[m * (size_t)N + ncol] = f2bf(v);
        } else if (EPI == 1) {
          const int tt = (int)(m >> 8), b = (int)(m & 255);
          const int q  = ncol >> 8, jc = ncol & 255;
          const int phh = jc >> 7, jl = jc & 127;
          ((u16*)outp)[(size_t)tt * 262144 + (size_t)(q >> 1) * 131072 +
                       (size_t)b * 512 + phh * 256 + (q & 1) * 128 + jl] =
              f2bf(v);
        } else {
          if (ncol < 32)
            ((float*)outp)[m * 32 + ncol] = tanhf(v);
          else
            ((float*)outp + 4194304)[m * 32 + ncol - 32] =
                log1pf(__expf(v)) + 1e-6f;
        }
      }
    }
}

// -------------------------------------------------------------- LSTM scan
// 32 blocks = 16 groups x 2. Group g owns batches [16g,16g+16); block half
// ph owns h-dims [128ph,128ph+128) -> 512 W_hh rows register-resident as
// MFMA B-fragments (256 KB/block). Per step: full h staged in LDS (own half
// from last epilogue, partner half via LLC atomics), 32 MFMAs/wave, gate
// math in fp32, h2 slice exchanged + flag released.
__global__ __launch_bounds__(512, 2) void lstm_scan(
    const u16* __restrict__ Whh,    // bf16 [1024][256]
    const int* __restrict__ dones,  // [512][256]
    const u16* ig,                  // bf16, ALIASES hid region (no restrict!)
    float* hid,                     // d_out + 8388608 floats (no restrict!)
    u16* __restrict__ pre_out,      // bf16 [131072][256] = leaky_relu(h2)
    u32* __restrict__ Xbuf,         // [16][2][16][256] bf16-in-u32
    u32* __restrict__ flags) {      // [32][16]
  const int tid  = threadIdx.x;
  const int w    = tid >> 6;
  const int lane = tid & 63;
  const int quad = lane >> 4, l15 = lane & 15;
  const int ph = blockIdx.x & 1, g = blockIdx.x >> 1;
  const int b0 = g * 16;
  const int jl   = w * 16 + l15;    // 0..127 local h-dim
  const int jcol = ph * 128 + jl;   // global h-dim
  const int pb = blockIdx.x ^ 1;    // partner block

  __shared__ __align__(16) u16 h_lds[16 * 264];  // [16 m][256 j + 8 pad]

  // --- persistent weight fragments: rows {q*256 + jcol}, q=i,f,g,o
  short8 wf[4][8];
#pragma unroll
  for (int q = 0; q < 4; q++) {
    const u16* wr = Whh + (size_t)(q * 256 + jcol) * 256;
#pragma unroll
    for (int kc = 0; kc < 8; kc++)
      wf[q][kc] = *(const short8*)(wr + kc * 32 + quad * 8);
  }

  float c4[4]   = {0.f, 0.f, 0.f, 0.f};
  float hown[4] = {0.f, 0.f, 0.f, 0.f};

  for (int i = tid; i < 16 * 264 / 2; i += 512) ((u32*)h_lds)[i] = 0;

  // --- prefetch t=0 (dones + ig, permuted layout)
  int dpf[5];
  u16 igpf[16];
  {
    const int* dr = dones + b0;
#pragma unroll
    for (int r = 0; r < 4; r++) dpf[r] = dr[quad * 4 + r];
    dpf[4] = dr[l15];
    const u16* igr = ig + (size_t)b0 * 512 + ph * 256 + jl;
#pragma unroll
    for (int q = 0; q < 4; q++)
#pragma unroll
      for (int r = 0; r < 4; r++)
        igpf[q * 4 + r] = igr[(size_t)(q >> 1) * 131072 +
                              (size_t)(quad * 4 + r) * 512 + (q & 1) * 128];
  }
  __syncthreads();

  const short8 z8 = {0, 0, 0, 0, 0, 0, 0, 0};

  for (int t = 0; t < 512; t++) {
    // keep masks for this step (dones prefetched last iter)
    float kc4[4];
#pragma unroll
    for (int r = 0; r < 4; r++) kc4[r] = dpf[r] ? 0.f : 1.f;
    const bool ka = (dpf[4] == 0);
    const int tn = (t < 511) ? t + 1 : 511;
    {
      const int* dr = dones + tn * 256 + b0;
#pragma unroll
      for (int r = 0; r < 4; r++) dpf[r] = dr[quad * 4 + r];
      dpf[4] = dr[l15];
    }

    // --- receive partner h2 half (t>0)
    if (t > 0) {
      if (tid == 0) {
        while (__hip_atomic_load(&flags[pb * 16], __ATOMIC_ACQUIRE,
                                 __HIP_MEMORY_SCOPE_AGENT) < (u32)t) {}
      }
      __syncthreads();
      const int m  = tid >> 5;
      const int jp = (1 - ph) * 128 + (tid & 31) * 4;
      const u32* xs = Xbuf + ((size_t)((g * 2 + (t & 1)) * 16 + m)) * 256 + jp;
      u32 v0 = __hip_atomic_load(xs + 0, __ATOMIC_RELAXED, __HIP_MEMORY_SCOPE_AGENT);
      u32 v1 = __hip_atomic_load(xs + 1, __ATOMIC_RELAXED, __HIP_MEMORY_SCOPE_AGENT);
      u32 v2 = __hip_atomic_load(xs + 2, __ATOMIC_RELAXED, __HIP_MEMORY_SCOPE_AGENT);
      u32 v3 = __hip_atomic_load(xs + 3, __ATOMIC_RELAXED, __HIP_MEMORY_SCOPE_AGENT);
      u16x4 pk; pk[0] = (u16)v0; pk[1] = (u16)v1; pk[2] = (u16)v2; pk[3] = (u16)v3;
      *(u16x4*)&h_lds[m * 264 + jp] = pk;
    }
    __syncthreads();

    // --- A fragments (h, masked by keep[l15])
    short8 af[8];
#pragma unroll
    for (int kc = 0; kc < 8; kc++)
      af[kc] = *(const short8*)&h_lds[l15 * 264 + kc * 32 + quad * 8];
    if (!ka) {
#pragma unroll
      for (int kc = 0; kc < 8; kc++) af[kc] = z8;
    }

    // mask own state (pre-step h,c after masking == hid[t])
#pragma unroll
    for (int r = 0; r < 4; r++) { c4[r] *= kc4[r]; hown[r] *= kc4[r]; }

    // acc init from prefetched ig[t] (forces waitcnt on those loads)
    f32x4 acc[4];
#pragma unroll
    for (int q = 0; q < 4; q++)
#pragma unroll
      for (int r = 0; r < 4; r++) acc[q][r] = bf2f(igpf[q * 4 + r]);

    // hid[t] writes — ig[t] loads (all threads) drained at the barrier that
    // preceded this point (vmcnt(0) before s_barrier); same bytes, safe.
    {
      float* h0 = hid + ((size_t)(t * 2) * 256 + b0) * 256 + jcol;
#pragma unroll
      for (int r = 0; r < 4; r++) {
        const int m = quad * 4 + r;
        h0[(size_t)m * 256] = hown[r];
        h0[(size_t)(256 + m) * 256] = c4[r];
      }
    }

    // prefetch ig[t+1] (skip at t=511: bytes already overwritten by hid)
    if (t < 511) {
      const u16* igr = ig + (size_t)(t + 1) * 262144 + (size_t)b0 * 512 +
                       ph * 256 + jl;
#pragma unroll
      for (int q = 0; q < 4; q++)
#pragma unroll
        for (int r = 0; r < 4; r++)
          igpf[q * 4 + r] = igr[(size_t)(q >> 1) * 131072 +
                                (size_t)(quad * 4 + r) * 512 + (q & 1) * 128];
    }

    // --- gates += h @ W^T  (32 MFMAs)
#pragma unroll
    for (int kc = 0; kc < 8; kc++)
#pragma unroll
      for (int q = 0; q < 4; q++)
        acc[q] = __builtin_amdgcn_mfma_f32_16x16x32_bf16(af[kc], wf[q][kc],
                                                         acc[q], 0, 0, 0);

    __syncthreads();   // all A-frag reads done before own-half overwrite

    // --- gate math + epilogue
    u16* pr = pre_out + ((size_t)t * 256 + b0) * 256 + jcol;
    u32* xo = Xbuf + ((size_t)((g * 2 + ((t + 1) & 1)) * 16)) * 256 + jcol;
#pragma unroll
    for (int r = 0; r < 4; r++) {
      const int m = quad * 4 + r;
      const float iv = acc[0][r], fv = acc[1][r], gv = acc[2][r], ov = acc[3][r];
      const float c2 = fsigmoid(fv) * c4[r] + fsigmoid(iv) * ftanh(gv);
      const float h2 = fsigmoid(ov) * ftanh(c2);
      c4[r] = c2;
      hown[r] = h2;
      const u16 hb = f2bf(h2);
      h_lds[m * 264 + jcol] = hb;                       // own half for t+1
      __hip_atomic_store(xo + (size_t)m * 256, (u32)hb, __ATOMIC_RELAXED,
                         __HIP_MEMORY_SCOPE_AGENT);
      const float pv = h2 > 0.0f ? h2 : 0.01f * h2;     // pre = lrelu(h2)
      pr[(size_t)m * 256] = f2bf(pv);
    }

    __syncthreads();   // drains all waves' X stores (vmcnt0 before barrier)
    if (tid == 0)
      __hip_atomic_store(&flags[blockIdx.x * 16], (u32)(t + 1),
                         __ATOMIC_RELEASE, __HIP_MEMORY_SCOPE_AGENT);
  }
}

// ---------------------------------------------------------------------------
extern "C" void kernel_launch(void* const* d_in, const int* in_sizes, int n_in,
                              void* d_out, int out_size, void* d_ws, size_t ws_size,
                              hipStream_t stream) {
  const float* x    = (const float*)d_in[0];
  const int*   dns  = (const int*)d_in[1];
  const float* W1   = (const float*)d_in[2];
  const float* b1   = (const float*)d_in[3];
  const float* Wih  = (const float*)d_in[4];
  const float* Whh  = (const float*)d_in[5];
  const float* bih  = (const float*)d_in[6];
  const float* bhh  = (const float*)d_in[7];
  const float* Wm   = (const float*)d_in[8];
  const float* bm   = (const float*)d_in[9];
  const float* Wsd  = (const float*)d_in[10];
  const float* bs   = (const float*)d_in[11];

  char* ws = (char*)d_ws;
  u16*   shb  = (u16*)(ws + OFF_SH);
  u16*   preb = (u16*)(ws + OFF_PRE);
  u16*   W1b  = (u16*)(ws + OFF_W1);
  u16*   Wihb = (u16*)(ws + OFF_WIH);
  u16*   Whhb = (u16*)(ws + OFF_WHH);
  u16*   Wcb  = (u16*)(ws + OFF_WCAT);
  float* bigv = (float*)(ws + OFF_BIG);
  float* bct  = (float*)(ws + OFF_BCAT);
  u32*   Xb   = (u32*)(ws + OFF_X);
  u32*   flg  = (u32*)(ws + OFF_FLAG);

  u16*   xb  = (u16*)d_out;                          // aliases means+stds
  u16*   igb = (u16*)((char*)d_out + 33554432);      // aliases hidden_outputs
  float* hid = (float*)d_out + 8388608;

  k_conv_x<<<512, 256, 0, stream>>>(x, xb);
  k_small<<<64, 256, 0, stream>>>(W1, Wih, Whh, Wm, Wsd, bih, bhh, bm, bs,
                                  W1b, Wihb, Whhb, Wcb, bigv, bct, flg);
  gemm_bt<128, 0><<<dim3(2048, 4), 256, 0, stream>>>(xb, W1b, b1, shb, 256);
  gemm_bt<256, 1><<<dim3(2048, 16), 256, 0, stream>>>(shb, Wihb, bigv, igb, 1024);
  lstm_scan<<<32, 512, 0, stream>>>(Whhb, dns, igb, hid, preb, Xb, flg);
  gemm_bt<256, 2><<<dim3(2048, 1), 256, 0, stream>>>(preb, Wcb, bct, d_out, 64);
}

// Round 3
// 2655.069 us; speedup vs baseline: 1.2711x; 1.2711x over previous
//
#include <hip/hip_runtime.h>

// ---------------------------------------------------------------------------
// GaussianGradientLSTMPolicy on MI355X
//   A0: fp32 -> bf16 converts (x, weights), bias fusions
//   A2: shared = leaky_relu(x @ W1^T + b1)                  [131072 x 256]
//   A3: ig     = shared @ W_ih^T + (b_ih + b_hh)  (permuted)[131072 x 1024]
//   B : persistent-register LSTM scan, block pairs exchange h halves via LLC
//       R3: tag-in-word relaxed atomics (no acquire/release -> no buffer_inv
//       / buffer_wbl2 L2 flushes on the critical path)
//   C : means = tanh(pre@Wm^T+bm), stds = softplus(pre@Ws^T+bs)+eps
// Aliasing:
//   - x_bf16 lives in d_out[0 .. 32MiB) (means+stds region), consumed by A2
//   - ig (bf16) lives in the d_out hidden_outputs region with a PERMUTED
//     layout such that the bytes block (g,ph) reads as ig[t] are exactly the
//     bytes it writes as hid[t]:
//       idx_u16(t,b,q,ph,jl) = t*262144 + (q>>1)*131072 + b*512
//                              + ph*256 + (q&1)*128 + jl
//     Per-block aliasing only; within a block the vmcnt(0) drain implied by
//     the post-receive __syncthreads orders all ig[t] loads (prefetched in
//     step t-1) before any hid[t] store (step t).
// ---------------------------------------------------------------------------

typedef __attribute__((ext_vector_type(8))) short short8;
typedef __attribute__((ext_vector_type(4))) float f32x4;
typedef __attribute__((ext_vector_type(4))) unsigned short u16x4;
typedef unsigned short u16;
typedef unsigned int   u32;

// ws layout (bytes)
constexpr size_t OFF_SH   = 0;                      // shared bf16   67108864
constexpr size_t OFF_PRE  = 67108864;               // pre bf16      67108864
constexpr size_t OFF_W1   = 134217728;              // W1 bf16          65536
constexpr size_t OFF_WIH  = OFF_W1   + 65536;       // W_ih bf16       524288
constexpr size_t OFF_WHH  = OFF_WIH  + 524288;      // W_hh bf16       524288
constexpr size_t OFF_WCAT = OFF_WHH  + 524288;      // [Wm;Ws] bf16     32768
constexpr size_t OFF_BIG  = OFF_WCAT + 32768;       // b_ih+b_hh f32     4096
constexpr size_t OFF_BCAT = OFF_BIG  + 4096;        // [bm;bs] f32        256
constexpr size_t OFF_X    = OFF_BCAT + 256;         // h2 exchange     524288
// total ~136 MB

__device__ __forceinline__ u16 f2bf(float f) {
  union { float f; u32 u; } v; v.f = f;
  u32 u = v.u;
  return (u16)((u + 0x7fffu + ((u >> 16) & 1u)) >> 16);   // RNE
}
__device__ __forceinline__ float bf2f(u16 h) {
  union { u32 u; float f; } v; v.u = ((u32)h) << 16; return v.f;
}
__device__ __forceinline__ float fsigmoid(float x) {
  return 1.0f / (1.0f + __expf(-x));
}
__device__ __forceinline__ float ftanh(float x) {
  return 1.0f - 2.0f / (__expf(2.0f * x) + 1.0f);
}

// ---------------------------------------------------------------- converts
__global__ void k_conv_x(const float* __restrict__ x, u16* __restrict__ o) {
  const size_t stride = (size_t)gridDim.x * blockDim.x;
  for (size_t i = (size_t)blockIdx.x * blockDim.x + threadIdx.x;
       i < 16777216 / 4; i += stride) {
    f32x4 v = ((const f32x4*)x)[i];
    u16x4 r;
    r[0] = f2bf(v[0]); r[1] = f2bf(v[1]); r[2] = f2bf(v[2]); r[3] = f2bf(v[3]);
    ((u16x4*)o)[i] = r;
  }
}

__global__ void k_small(const float* __restrict__ W1, const float* __restrict__ Wih,
                        const float* __restrict__ Whh, const float* __restrict__ Wm,
                        const float* __restrict__ Ws,  const float* __restrict__ bih,
                        const float* __restrict__ bhh, const float* __restrict__ bm,
                        const float* __restrict__ bs,
                        u16* __restrict__ W1b, u16* __restrict__ Wihb,
                        u16* __restrict__ Whhb, u16* __restrict__ Wcatb,
                        float* __restrict__ bigv, float* __restrict__ bcatv) {
  const int stride = gridDim.x * blockDim.x;
  const int i0 = blockIdx.x * blockDim.x + threadIdx.x;
  for (int i = i0; i < 32768;  i += stride) W1b[i]  = f2bf(W1[i]);
  for (int i = i0; i < 262144; i += stride) Wihb[i] = f2bf(Wih[i]);
  for (int i = i0; i < 262144; i += stride) Whhb[i] = f2bf(Whh[i]);
  for (int i = i0; i < 8192;   i += stride) Wcatb[i]        = f2bf(Wm[i]);
  for (int i = i0; i < 8192;   i += stride) Wcatb[8192 + i] = f2bf(Ws[i]);
  for (int i = i0; i < 1024;   i += stride) bigv[i] = bih[i] + bhh[i];
  for (int i = i0; i < 32;     i += stride) bcatv[i]      = bm[i];
  for (int i = i0; i < 32;     i += stride) bcatv[32 + i] = bs[i];
}

// ------------------------------------------------------------ generic GEMM
// C[M,N] = epi(A[M,K] @ W[N,K]^T + bias), bf16 in, fp32 acc.
// EPI 0: leaky_relu -> bf16 out (ld = N)
// EPI 1: bf16 out, permuted so scan-block (g,ph)'s ig[t] bytes == its hid[t]
// EPI 2: heads: n<32 -> tanh -> means(f32); n>=32 -> softplus+eps -> stds
template <int K, int EPI>
__global__ __launch_bounds__(256) void gemm_bt(const u16* __restrict__ A,
                                               const u16* __restrict__ W,
                                               const float* __restrict__ bias,
                                               void* __restrict__ outp, int N) {
  __shared__ __align__(16) u16 As[64 * 40];   // +8 pad: 2-way banks only
  __shared__ __align__(16) u16 Wt[64 * 40];
  const int tid  = threadIdx.x;
  const int lane = tid & 63;
  const int wv   = tid >> 6;
  const int quad = lane >> 4, l15 = lane & 15;
  const int wm = wv & 1, wn = wv >> 1;
  const size_t m0 = (size_t)blockIdx.x * 64;
  const int    n0 = blockIdx.y * 64;
  const int ldr  = tid >> 2;
  const int lseg = (tid & 3) * 8;

  const u16* Ag = A + (m0 + ldr) * K + lseg;
  const u16* Wg = W + (size_t)(n0 + ldr) * K + lseg;

  f32x4 acc[2][2] = {};

#pragma unroll 1
  for (int kc = 0; kc < K; kc += 32) {
    *(short8*)&As[ldr * 40 + lseg] = *(const short8*)(Ag + kc);
    *(short8*)&Wt[ldr * 40 + lseg] = *(const short8*)(Wg + kc);
    __syncthreads();
    short8 a0 = *(const short8*)&As[(wm * 32 + l15) * 40 + quad * 8];
    short8 a1 = *(const short8*)&As[(wm * 32 + 16 + l15) * 40 + quad * 8];
    short8 b0 = *(const short8*)&Wt[(wn * 32 + l15) * 40 + quad * 8];
    short8 b1 = *(const short8*)&Wt[(wn * 32 + 16 + l15) * 40 + quad * 8];
    acc[0][0] = __builtin_amdgcn_mfma_f32_16x16x32_bf16(a0, b0, acc[0][0], 0, 0, 0);
    acc[1][0] = __builtin_amdgcn_mfma_f32_16x16x32_bf16(a1, b0, acc[1][0], 0, 0, 0);
    acc[0][1] = __builtin_amdgcn_mfma_f32_16x16x32_bf16(a0, b1, acc[0][1], 0, 0, 0);
    acc[1][1] = __builtin_amdgcn_mfma_f32_16x16x32_bf16(a1, b1, acc[1][1], 0, 0, 0);
    __syncthreads();
  }

#pragma unroll
  for (int mi = 0; mi < 2; mi++)
#pragma unroll
    for (int ni = 0; ni < 2; ni++) {
      const int nl   = wn * 32 + ni * 16 + l15;   // 0..63 within tile
      const int ncol = n0 + nl;                   // global col
      const float bv = bias[ncol];
#pragma unroll
      for (int r = 0; r < 4; r++) {
        const size_t m = m0 + wm * 32 + mi * 16 + quad * 4 + r;
        float v = acc[mi][ni][r] + bv;
        if (EPI == 0) {
          v = v > 0.0f ? v : 0.01f * v;
          ((u16*)outp)[m * (size_t)N + ncol] = f2bf(v);
        } else if (EPI == 1) {
          const int tt = (int)(m >> 8), b = (int)(m & 255);
          const int q  = ncol >> 8, jc = ncol & 255;
          const int phh = jc >> 7, jl = jc & 127;
          ((u16*)outp)[(size_t)tt * 262144 + (size_t)(q >> 1) * 131072 +
                       (size_t)b * 512 + phh * 256 + (q & 1) * 128 + jl] =
              f2bf(v);
        } else {
          if (ncol < 32)
            ((float*)outp)[m * 32 + ncol] = tanhf(v);
          else
            ((float*)outp + 4194304)[m * 32 + ncol - 32] =
                log1pf(__expf(v)) + 1e-6f;
        }
      }
    }
}

// -------------------------------------------------------------- LSTM scan
// 32 blocks = 16 groups x 2. Group g owns batches [16g,16g+16); block half
// ph owns h-dims [128ph,128ph+128) -> 512 W_hh rows register-resident as
// MFMA B-fragments (256 KB/block). Per step: full h staged in LDS (own half
// from last epilogue, partner half via LLC), 32 MFMAs/wave, gate math fp32.
// Exchange protocol: each u32 word = bf16(h2) | ((t+1)<<16). Purely relaxed
// agent-scope atomics (sc1 -> write-through/read-from LLC): data+tag are one
// atomic word, so no fences, no L2 flush/invalidate, no separate flag trip.
// Parity double-buffer prevents tag t+2 clobbering unconsumed tag t (the
// producer's t+2 write is data-dependent on the consumer's t+1 output).
__global__ __launch_bounds__(512, 2) void lstm_scan(
    const u16* __restrict__ Whh,    // bf16 [1024][256]
    const int* __restrict__ dones,  // [512][256]
    const u16* ig,                  // bf16, ALIASES hid region (no restrict!)
    float* hid,                     // d_out + 8388608 floats (no restrict!)
    u16* __restrict__ pre_out,      // bf16 [131072][256] = leaky_relu(h2)
    u32* __restrict__ Xbuf) {       // [16 groups][2 parity][16 m][256 jcol]
  const int tid  = threadIdx.x;
  const int w    = tid >> 6;
  const int lane = tid & 63;
  const int quad = lane >> 4, l15 = lane & 15;
  const int ph = blockIdx.x & 1, g = blockIdx.x >> 1;
  const int b0 = g * 16;
  const int jl   = w * 16 + l15;    // 0..127 local h-dim
  const int jcol = ph * 128 + jl;   // global h-dim

  __shared__ __align__(16) u16 h_lds[16 * 264];  // [16 m][256 j + 8 pad]

  // --- persistent weight fragments: rows {q*256 + jcol}, q=i,f,g,o
  short8 wf[4][8];
#pragma unroll
  for (int q = 0; q < 4; q++) {
    const u16* wr = Whh + (size_t)(q * 256 + jcol) * 256;
#pragma unroll
    for (int kc = 0; kc < 8; kc++)
      wf[q][kc] = *(const short8*)(wr + kc * 32 + quad * 8);
  }

  float c4[4]   = {0.f, 0.f, 0.f, 0.f};
  float hown[4] = {0.f, 0.f, 0.f, 0.f};

  for (int i = tid; i < 16 * 264 / 2; i += 512) ((u32*)h_lds)[i] = 0;

  // --- prefetch t=0 (dones + ig, permuted layout)
  int dpf[5];
  u16 igpf[16];
  {
    const int* dr = dones + b0;
#pragma unroll
    for (int r = 0; r < 4; r++) dpf[r] = dr[quad * 4 + r];
    dpf[4] = dr[l15];
    const u16* igr = ig + (size_t)b0 * 512 + ph * 256 + jl;
#pragma unroll
    for (int q = 0; q < 4; q++)
#pragma unroll
      for (int r = 0; r < 4; r++)
        igpf[q * 4 + r] = igr[(size_t)(q >> 1) * 131072 +
                              (size_t)(quad * 4 + r) * 512 + (q & 1) * 128];
  }
  __syncthreads();

  const short8 z8 = {0, 0, 0, 0, 0, 0, 0, 0};

  for (int t = 0; t < 512; t++) {
    // keep masks for this step (dones prefetched last iter)
    float kc4[4];
#pragma unroll
    for (int r = 0; r < 4; r++) kc4[r] = dpf[r] ? 0.f : 1.f;
    const bool ka = (dpf[4] == 0);
    const int tn = (t < 511) ? t + 1 : 511;
    {
      const int* dr = dones + tn * 256 + b0;
#pragma unroll
      for (int r = 0; r < 4; r++) dpf[r] = dr[quad * 4 + r];
      dpf[4] = dr[l15];
    }

    // --- receive partner h2 half (t>0): per-thread poll on tagged words
    if (t > 0) {
      const int m  = tid >> 5;
      const int jp = (1 - ph) * 128 + (tid & 31) * 4;
      const u32* xs = Xbuf + ((size_t)((g * 2 + (t & 1)) * 16 + m)) * 256 + jp;
      const u32 want = (u32)t << 16;
      u32 v0, v1, v2, v3;
      for (;;) {
        v0 = __hip_atomic_load(xs + 0, __ATOMIC_RELAXED, __HIP_MEMORY_SCOPE_AGENT);
        v1 = __hip_atomic_load(xs + 1, __ATOMIC_RELAXED, __HIP_MEMORY_SCOPE_AGENT);
        v2 = __hip_atomic_load(xs + 2, __ATOMIC_RELAXED, __HIP_MEMORY_SCOPE_AGENT);
        v3 = __hip_atomic_load(xs + 3, __ATOMIC_RELAXED, __HIP_MEMORY_SCOPE_AGENT);
        const u32 bad = ((v0 ^ want) | (v1 ^ want) | (v2 ^ want) | (v3 ^ want)) >> 16;
        if (bad == 0) break;
      }
      u16x4 pk; pk[0] = (u16)v0; pk[1] = (u16)v1; pk[2] = (u16)v2; pk[3] = (u16)v3;
      *(u16x4*)&h_lds[m * 264 + jp] = pk;
    }
    __syncthreads();   // orders LDS; implied vmcnt(0) drains ig[t] loads
                       // before the hid[t] stores below (alias safety)

    // --- A fragments (h, masked by keep[l15])
    short8 af[8];
#pragma unroll
    for (int kc = 0; kc < 8; kc++)
      af[kc] = *(const short8*)&h_lds[l15 * 264 + kc * 32 + quad * 8];
    if (!ka) {
#pragma unroll
      for (int kc = 0; kc < 8; kc++) af[kc] = z8;
    }

    // mask own state (pre-step h,c after masking == hid[t])
#pragma unroll
    for (int r = 0; r < 4; r++) { c4[r] *= kc4[r]; hown[r] *= kc4[r]; }

    // acc init from prefetched ig[t]
    f32x4 acc[4];
#pragma unroll
    for (int q = 0; q < 4; q++)
#pragma unroll
      for (int r = 0; r < 4; r++) acc[q][r] = bf2f(igpf[q * 4 + r]);

    // hid[t] writes — every thread's ig[t] loads drained at the barrier
    // above; same byte set per block, disjoint across blocks.
    {
      float* h0 = hid + ((size_t)(t * 2) * 256 + b0) * 256 + jcol;
#pragma unroll
      for (int r = 0; r < 4; r++) {
        const int m = quad * 4 + r;
        h0[(size_t)m * 256] = hown[r];
        h0[(size_t)(256 + m) * 256] = c4[r];
      }
    }

    // prefetch ig[t+1] (skip at t=511: bytes already overwritten by hid)
    if (t < 511) {
      const u16* igr = ig + (size_t)(t + 1) * 262144 + (size_t)b0 * 512 +
                       ph * 256 + jl;
#pragma unroll
      for (int q = 0; q < 4; q++)
#pragma unroll
        for (int r = 0; r < 4; r++)
          igpf[q * 4 + r] = igr[(size_t)(q >> 1) * 131072 +
                                (size_t)(quad * 4 + r) * 512 + (q & 1) * 128];
    }

    // --- gates += h @ W^T  (32 MFMAs)
#pragma unroll
    for (int kc = 0; kc < 8; kc++)
#pragma unroll
      for (int q = 0; q < 4; q++)
        acc[q] = __builtin_amdgcn_mfma_f32_16x16x32_bf16(af[kc], wf[q][kc],
                                                         acc[q], 0, 0, 0);

    __syncthreads();   // all A-frag reads done before own-half overwrite

    // --- gate math + epilogue (X store ASAP: it's the critical path)
    u16* pr = pre_out + ((size_t)t * 256 + b0) * 256 + jcol;
    u32* xo = Xbuf + ((size_t)((g * 2 + ((t + 1) & 1)) * 16)) * 256 + jcol;
    const u32 tagw = (u32)(t + 1) << 16;
#pragma unroll
    for (int r = 0; r < 4; r++) {
      const int m = quad * 4 + r;
      const float iv = acc[0][r], fv = acc[1][r], gv = acc[2][r], ov = acc[3][r];
      const float c2 = fsigmoid(fv) * c4[r] + fsigmoid(iv) * ftanh(gv);
      const float h2 = fsigmoid(ov) * ftanh(c2);
      c4[r] = c2;
      hown[r] = h2;
      const u16 hb = f2bf(h2);
      __hip_atomic_store(xo + (size_t)m * 256, (u32)hb | tagw, __ATOMIC_RELAXED,
                         __HIP_MEMORY_SCOPE_AGENT);
      h_lds[m * 264 + jcol] = hb;                       // own half for t+1
      const float pv = h2 > 0.0f ? h2 : 0.01f * h2;     // pre = lrelu(h2)
      pr[(size_t)m * 256] = f2bf(pv);
    }
    // no trailing barrier: next step's post-receive barrier orders LDS, and
    // the tag-in-word protocol needs no store drain before a flag.
  }
}

// ---------------------------------------------------------------------------
extern "C" void kernel_launch(void* const* d_in, const int* in_sizes, int n_in,
                              void* d_out, int out_size, void* d_ws, size_t ws_size,
                              hipStream_t stream) {
  const float* x    = (const float*)d_in[0];
  const int*   dns  = (const int*)d_in[1];
  const float* W1   = (const float*)d_in[2];
  const float* b1   = (const float*)d_in[3];
  const float* Wih  = (const float*)d_in[4];
  const float* Whh  = (const float*)d_in[5];
  const float* bih  = (const float*)d_in[6];
  const float* bhh  = (const float*)d_in[7];
  const float* Wm   = (const float*)d_in[8];
  const float* bm   = (const float*)d_in[9];
  const float* Wsd  = (const float*)d_in[10];
  const float* bs   = (const float*)d_in[11];

  char* ws = (char*)d_ws;
  u16*   shb  = (u16*)(ws + OFF_SH);
  u16*   preb = (u16*)(ws + OFF_PRE);
  u16*   W1b  = (u16*)(ws + OFF_W1);
  u16*   Wihb = (u16*)(ws + OFF_WIH);
  u16*   Whhb = (u16*)(ws + OFF_WHH);
  u16*   Wcb  = (u16*)(ws + OFF_WCAT);
  float* bigv = (float*)(ws + OFF_BIG);
  float* bct  = (float*)(ws + OFF_BCAT);
  u32*   Xb   = (u32*)(ws + OFF_X);

  u16*   xb  = (u16*)d_out;                          // aliases means+stds
  u16*   igb = (u16*)((char*)d_out + 33554432);      // aliases hidden_outputs
  float* hid = (float*)d_out + 8388608;

  k_conv_x<<<512, 256, 0, stream>>>(x, xb);
  k_small<<<64, 256, 0, stream>>>(W1, Wih, Whh, Wm, Wsd, bih, bhh, bm, bs,
                                  W1b, Wihb, Whhb, Wcb, bigv, bct);
  gemm_bt<128, 0><<<dim3(2048, 4), 256, 0, stream>>>(xb, W1b, b1, shb, 256);
  gemm_bt<256, 1><<<dim3(2048, 16), 256, 0, stream>>>(shb, Wihb, bigv, igb, 1024);
  lstm_scan<<<32, 512, 0, stream>>>(Whhb, dns, igb, hid, preb, Xb);
  gemm_bt<256, 2><<<dim3(2048, 1), 256, 0, stream>>>(preb, Wcb, bct, d_out, 64);
}